// Round 1
// baseline (1056.574 us; speedup 1.0000x reference)
//
#include <hip/hip_runtime.h>
#include <hip/hip_bf16.h>
#include <stdint.h>
#include <stddef.h>

// ---------------------------------------------------------------------------
// Swin-V2 window attention, MI355X.
// Pipeline: [split weights to bf16 hi/lo] [CPB MLP -> rpb table]
//   per batch-slice: [split x] -> [QKV GEMM bf16x2 MFMA] -> [fp32 attention]
//                    -> [proj GEMM bf16x2 MFMA]
// bf16x2 trick: A*B ~= Ah*Bh + Ah*Bl + Al*Bh (3 K-phases into same acc),
// keeps fp32-level accuracy while using the 2.5PF bf16 MFMA pipe.
// ---------------------------------------------------------------------------

typedef unsigned short ushort_t;
typedef __attribute__((ext_vector_type(8))) short short8;   // 8 bf16 (4 VGPRs)
typedef __attribute__((ext_vector_type(4))) float f32x4;

#define NWIN   1024
#define NTOK   64
#define CDIM   512
#define NHEAD  16
#define HDIM   32
#define MROWS  65536      // NWIN*NTOK

__device__ __forceinline__ ushort_t f2bf(float x) {
  union { float f; unsigned u; } c; c.f = x;
  unsigned r = (c.u + 0x7fffu + ((c.u >> 16) & 1u)) >> 16;   // RNE
  return (ushort_t)r;
}
__device__ __forceinline__ float bf2f(ushort_t h) {
  union { unsigned u; float f; } c; c.u = ((unsigned)h) << 16;
  return c.f;
}

// ---------------- split fp32 -> bf16 hi + bf16 lo --------------------------
__global__ __launch_bounds__(256) void k_split(const float* __restrict__ src,
                                               ushort_t* __restrict__ hi,
                                               ushort_t* __restrict__ lo, int n4) {
  int stride = gridDim.x * blockDim.x;
  for (int i = blockIdx.x * blockDim.x + threadIdx.x; i < n4; i += stride) {
    f32x4 x = reinterpret_cast<const f32x4*>(src)[i];
    ushort_t h4[4], l4[4];
#pragma unroll
    for (int j = 0; j < 4; ++j) {
      ushort_t h = f2bf(x[j]);
      h4[j] = h;
      l4[j] = f2bf(x[j] - bf2f(h));
    }
    uint2 hv = make_uint2(h4[0] | ((unsigned)h4[1] << 16), h4[2] | ((unsigned)h4[3] << 16));
    uint2 lv = make_uint2(l4[0] | ((unsigned)l4[1] << 16), l4[2] | ((unsigned)l4[3] << 16));
    reinterpret_cast<uint2*>(hi)[i] = hv;
    reinterpret_cast<uint2*>(lo)[i] = lv;
  }
}

// ---------------- CPB MLP: 225 positions -> 16*sigmoid table ---------------
__global__ __launch_bounds__(256) void k_cpb1(const float* __restrict__ coords, // (225,2)
                                              const float* __restrict__ w1,     // (512,2)
                                              const float* __restrict__ b1,     // (512)
                                              const float* __restrict__ w2,     // (16,512)
                                              float* __restrict__ tbl) {        // (225,16)
  __shared__ float hid[512];
  int p = blockIdx.x;
  float c0 = coords[2 * p], c1 = coords[2 * p + 1];
  int t = threadIdx.x;
  for (int j = t; j < 512; j += 256) {
    float v = c0 * w1[2 * j] + c1 * w1[2 * j + 1] + b1[j];
    hid[j] = v > 0.f ? v : 0.f;
  }
  __syncthreads();
  int wid = t >> 6, lane = t & 63;
#pragma unroll
  for (int hh = 0; hh < 4; ++hh) {
    int head = wid * 4 + hh;
    float s = 0.f;
    for (int j = lane; j < 512; j += 64) s += hid[j] * w2[head * 512 + j];
#pragma unroll
    for (int off = 32; off > 0; off >>= 1) s += __shfl_xor(s, off);
    if (lane == 0) tbl[p * 16 + head] = 16.f / (1.f + __expf(-s));
  }
}

// gather: rpb[h][n*64+m] = tbl[ridx[n*64+m]][h]
__global__ __launch_bounds__(256) void k_cpb2(const float* __restrict__ tbl,
                                              const int* __restrict__ ridx,
                                              float* __restrict__ rpb) {
  int idx = blockIdx.x * 256 + threadIdx.x;   // 65536 = 16*4096
  int h = idx >> 12, nm = idx & 4095;
  rpb[idx] = tbl[ridx[nm] * 16 + h];
}

// ---------------- GEMM: C[M,Nout] = A[M,K] * B[Nout,K]^T (bf16x2) ----------
__device__ __forceinline__ void gload16(const void* g, void* l) {
  __builtin_amdgcn_global_load_lds(
      (const __attribute__((address_space(1))) unsigned int*)g,
      (__attribute__((address_space(3))) unsigned int*)l, 16, 0, 0);
}

// EPI 0: qkv epilogue (scatter into q/k/v (B,nh,N,hd) + swin qkv bias)
// EPI 1: plain epilogue (out[m*Nout+col] + bias)
template <int EPI>
__global__ __launch_bounds__(256) void k_gemm(
    const ushort_t* __restrict__ Ah, const ushort_t* __restrict__ Al,
    const ushort_t* __restrict__ Bh, const ushort_t* __restrict__ Bl,
    int ntilesN,
    const float* __restrict__ qb, const float* __restrict__ vb,
    float* __restrict__ oq, float* __restrict__ ok, float* __restrict__ ov,
    const float* __restrict__ pb, float* __restrict__ oplain) {
  constexpr int K = 512;
  __shared__ ushort_t ldsA[2][128 * 32];
  __shared__ ushort_t ldsB[2][128 * 32];

  int nwg = gridDim.x;
  int bid = blockIdx.x;
  // XCD-chunked swizzle (all our grids are %8==0)
  int tile = ((nwg & 7) == 0) ? ((bid & 7) * (nwg >> 3) + (bid >> 3)) : bid;
  int tm = tile / ntilesN, tn = tile % ntilesN;

  int tid = threadIdx.x;
  int wid = tid >> 6, lane = tid & 63;
  int wr = wid >> 1, wc = wid & 1;
  int lr = lane & 15, lq = lane >> 4;

  f32x4 acc[4][4];
#pragma unroll
  for (int i = 0; i < 4; ++i)
#pragma unroll
    for (int j = 0; j < 4; ++j)
#pragma unroll
      for (int r = 0; r < 4; ++r) acc[i][j][r] = 0.f;

  auto stage = [&](int t, int bsel) {
    int phase = t >> 4;
    int k0 = (t & 15) << 5;
    const ushort_t* A = (phase == 2) ? Al : Ah;
    const ushort_t* B = (phase == 1) ? Bl : Bh;
#pragma unroll
    for (int is = 0; is < 2; ++is) {
      int c = is * 256 + tid;              // 16B chunk id, 0..511
      int row = c >> 2;
      int gc16 = (c & 3) ^ (row & 3);      // XOR swizzle on the SOURCE side
      const ushort_t* ga = A + ((size_t)(tm * 128 + row)) * K + k0 + gc16 * 8;
      gload16(ga, &ldsA[bsel][(is * 256 + wid * 64) * 8]);
      const ushort_t* gb = B + ((size_t)(tn * 128 + row)) * K + k0 + gc16 * 8;
      gload16(gb, &ldsB[bsel][(is * 256 + wid * 64) * 8]);
    }
  };

  stage(0, 0);
  for (int t = 0; t < 48; ++t) {
    __syncthreads();
    if (t + 1 < 48) stage(t + 1, (t + 1) & 1);
    int bsel = t & 1;
    int c16 = lq ^ (lr & 3);               // inverse swizzle on the READ side
    short8 a[4], b[4];
#pragma unroll
    for (int i = 0; i < 4; ++i) {
      int row = wr * 64 + i * 16 + lr;
      a[i] = *(const short8*)&ldsA[bsel][row * 32 + c16 * 8];
    }
#pragma unroll
    for (int j = 0; j < 4; ++j) {
      int row = wc * 64 + j * 16 + lr;
      b[j] = *(const short8*)&ldsB[bsel][row * 32 + c16 * 8];
    }
#pragma unroll
    for (int i = 0; i < 4; ++i)
#pragma unroll
      for (int j = 0; j < 4; ++j)
        acc[i][j] = __builtin_amdgcn_mfma_f32_16x16x32_bf16(a[i], b[j], acc[i][j], 0, 0, 0);
  }

  // C/D layout (m89/m91-verified): col = lane&15, row = (lane>>4)*4 + reg
#pragma unroll
  for (int i = 0; i < 4; ++i)
#pragma unroll
    for (int j = 0; j < 4; ++j) {
      int col = tn * 128 + wc * 64 + j * 16 + lr;
      if constexpr (EPI == 0) {
        int sec = col >> 9;
        int hcol = (col >> 5) & 15;
        int d = col & 31;
        float bias = (sec == 0) ? qb[col] : (sec == 2 ? vb[col & 511] : 0.f);
        float* outp = (sec == 0) ? oq : (sec == 1 ? ok : ov);
#pragma unroll
        for (int r = 0; r < 4; ++r) {
          int m = tm * 128 + wr * 64 + i * 16 + lq * 4 + r;
          int bwin = m >> 6, n = m & 63;
          outp[((((size_t)bwin * 16 + hcol) << 6) + n) * 32 + d] = acc[i][j][r] + bias;
        }
      } else {
        int Nout = ntilesN * 128;
        float bias = pb[col];
#pragma unroll
        for (int r = 0; r < 4; ++r) {
          int m = tm * 128 + wr * 64 + i * 16 + lq * 4 + r;
          oplain[(size_t)m * Nout + col] = acc[i][j][r] + bias;
        }
      }
    }
}

// ---------------- fp32 attention: one block per (window, head) -------------
__global__ __launch_bounds__(256) void k_attn(
    const float* __restrict__ q, const float* __restrict__ k,
    const float* __restrict__ v, const float* __restrict__ rpb,
    const float* __restrict__ lsc,
    ushort_t* __restrict__ aoh, ushort_t* __restrict__ aol) {
  __shared__ float qs[64][36];   // padded strides -> conflict-free f32x4 reads
  __shared__ float kt[32][68];   // K transposed: kt[d][m]
  __shared__ float vs[64][36];
  __shared__ float sb[64][65];
  int bh = blockIdx.x;
  int h = bh & 15, blw = bh >> 4;
  int t = threadIdx.x;
  size_t base = (size_t)bh << 11;   // *2048
#pragma unroll
  for (int i = 0; i < 2; ++i) {
    int idx = t + (i << 8);
    int row = idx >> 3, c4 = (idx & 7) << 2;
    f32x4 qv = *reinterpret_cast<const f32x4*>(q + base + row * 32 + c4);
    *reinterpret_cast<f32x4*>(&qs[row][c4]) = qv;
    f32x4 vv = *reinterpret_cast<const f32x4*>(v + base + row * 32 + c4);
    *reinterpret_cast<f32x4*>(&vs[row][c4]) = vv;
    f32x4 kv = *reinterpret_cast<const f32x4*>(k + base + row * 32 + c4);
    kt[c4 + 0][row] = kv[0];
    kt[c4 + 1][row] = kv[1];
    kt[c4 + 2][row] = kv[2];
    kt[c4 + 3][row] = kv[3];
  }
  float ls = lsc[h];
  __syncthreads();

  // scores: 4x4 register tile per thread
  int r0 = (t >> 4) << 2;
  int c0 = (t & 15) << 2;
  f32x4 acc[4];
#pragma unroll
  for (int i = 0; i < 4; ++i)
#pragma unroll
    for (int j = 0; j < 4; ++j) acc[i][j] = 0.f;
  for (int d4 = 0; d4 < 8; ++d4) {
    f32x4 qv[4], kv[4];
#pragma unroll
    for (int i = 0; i < 4; ++i) qv[i] = *reinterpret_cast<const f32x4*>(&qs[r0 + i][d4 << 2]);
#pragma unroll
    for (int dd = 0; dd < 4; ++dd) kv[dd] = *reinterpret_cast<const f32x4*>(&kt[(d4 << 2) + dd][c0]);
#pragma unroll
    for (int i = 0; i < 4; ++i)
#pragma unroll
      for (int dd = 0; dd < 4; ++dd) acc[i] += qv[i][dd] * kv[dd];
  }
  const float* rb = rpb + ((size_t)h << 12);
#pragma unroll
  for (int i = 0; i < 4; ++i)
#pragma unroll
    for (int j = 0; j < 4; ++j)
      sb[r0 + i][c0 + j] = acc[i][j] * ls + rb[(r0 + i) * 64 + c0 + j];
  __syncthreads();

  // softmax: 4 threads per row, 16 cols each
  {
    int rr = t >> 2, qd = t & 3;
    float* srow = &sb[rr][qd << 4];
    float ev[16];
    float mx = -1e30f;
#pragma unroll
    for (int j = 0; j < 16; ++j) mx = fmaxf(mx, srow[j]);
    mx = fmaxf(mx, __shfl_xor(mx, 1));
    mx = fmaxf(mx, __shfl_xor(mx, 2));
    float sum = 0.f;
#pragma unroll
    for (int j = 0; j < 16; ++j) { ev[j] = __expf(srow[j] - mx); sum += ev[j]; }
    sum += __shfl_xor(sum, 1);
    sum += __shfl_xor(sum, 2);
    float inv = 1.f / sum;
#pragma unroll
    for (int j = 0; j < 16; ++j) srow[j] = ev[j] * inv;
  }
  __syncthreads();

  // AV: each thread -> row n, 8 cols
  int n = t >> 2, d0 = (t & 3) << 3;
  f32x4 oa, oc;
#pragma unroll
  for (int r = 0; r < 4; ++r) { oa[r] = 0.f; oc[r] = 0.f; }
  for (int m = 0; m < 64; ++m) {
    float p = sb[n][m];
    f32x4 va = *reinterpret_cast<const f32x4*>(&vs[m][d0]);
    f32x4 vb2 = *reinterpret_cast<const f32x4*>(&vs[m][d0 + 4]);
    oa += va * p;
    oc += vb2 * p;
  }
  float ovals[8] = {oa[0], oa[1], oa[2], oa[3], oc[0], oc[1], oc[2], oc[3]};
  unsigned hw[4], lw[4];
#pragma unroll
  for (int j2 = 0; j2 < 4; ++j2) {
    ushort_t hA = f2bf(ovals[2 * j2]), hB = f2bf(ovals[2 * j2 + 1]);
    ushort_t lA = f2bf(ovals[2 * j2] - bf2f(hA));
    ushort_t lB = f2bf(ovals[2 * j2 + 1] - bf2f(hB));
    hw[j2] = hA | ((unsigned)hB << 16);
    lw[j2] = lA | ((unsigned)lB << 16);
  }
  size_t off = (((size_t)blw << 6) + n) * 512 + (h << 5) + d0;
  *reinterpret_cast<uint4*>(aoh + off) = make_uint4(hw[0], hw[1], hw[2], hw[3]);
  *reinterpret_cast<uint4*>(aol + off) = make_uint4(lw[0], lw[1], lw[2], lw[3]);
}

// ---------------------------------------------------------------------------
extern "C" void kernel_launch(void* const* d_in, const int* in_sizes, int n_in,
                              void* d_out, int out_size, void* d_ws, size_t ws_size,
                              hipStream_t stream) {
  const float* x      = (const float*)d_in[0];
  const float* qkvw   = (const float*)d_in[1];
  const float* qb     = (const float*)d_in[2];
  const float* vb     = (const float*)d_in[3];
  const float* lsc    = (const float*)d_in[4];
  const float* w1     = (const float*)d_in[5];
  const float* b1     = (const float*)d_in[6];
  const float* w2     = (const float*)d_in[7];
  const float* pw     = (const float*)d_in[8];
  const float* pb     = (const float*)d_in[9];
  const float* coords = (const float*)d_in[10];
  const int*   ridx   = (const int*)d_in[11];
  float* out = (float*)d_out;
  char* ws = (char*)d_ws;

  size_t off = 0;
  auto alloc = [&](size_t bytes) {
    size_t r = off;
    off = (off + bytes + 255) & ~(size_t)255;
    return r;
  };
  size_t oWQH = alloc((size_t)1536 * 512 * 2);
  size_t oWQL = alloc((size_t)1536 * 512 * 2);
  size_t oWPH = alloc((size_t)512 * 512 * 2);
  size_t oWPL = alloc((size_t)512 * 512 * 2);
  size_t oRPB = alloc((size_t)16 * 4096 * 4);
  size_t oTBL = alloc((size_t)225 * 16 * 4);
  size_t fixed = off;

  // choose slice count so scratch fits ws_size
  int S = 1;
  while (S <= 32) {
    size_t Ms = (size_t)MROWS / S;
    size_t need = fixed + Ms * 512 * 2 * 2 /*x hi/lo*/ + Ms * 512 * 4 * 3 /*q,k,v*/ + 4096;
    if (need <= ws_size) break;
    S <<= 1;
  }
  if (S > 64) S = 64;
  size_t Ms = (size_t)MROWS / S;

  size_t oXH = alloc(Ms * 512 * 2);
  size_t oXL = alloc(Ms * 512 * 2);
  size_t oQ  = alloc(Ms * 512 * 4);
  size_t oK  = alloc(Ms * 512 * 4);
  size_t oV  = alloc(Ms * 512 * 4);

  ushort_t* wqh = (ushort_t*)(ws + oWQH);
  ushort_t* wql = (ushort_t*)(ws + oWQL);
  ushort_t* wph = (ushort_t*)(ws + oWPH);
  ushort_t* wpl = (ushort_t*)(ws + oWPL);
  float* rpb = (float*)(ws + oRPB);
  float* tbl = (float*)(ws + oTBL);
  ushort_t* xh = (ushort_t*)(ws + oXH);
  ushort_t* xl = (ushort_t*)(ws + oXL);
  float* q = (float*)(ws + oQ);
  float* k = (float*)(ws + oK);
  float* v = (float*)(ws + oV);

  k_split<<<768, 256, 0, stream>>>(qkvw, wqh, wql, 1536 * 512 / 4);
  k_split<<<256, 256, 0, stream>>>(pw, wph, wpl, 512 * 512 / 4);
  k_cpb1<<<225, 256, 0, stream>>>(coords, w1, b1, w2, tbl);
  k_cpb2<<<256, 256, 0, stream>>>(tbl, ridx, rpb);

  int n4x = (int)(Ms * 512 / 4);
  int gsplit = (n4x + 255) / 256;
  if (gsplit > 2048) gsplit = 2048;
  int gq = (int)(Ms / 128) * 12;
  int gp = (int)(Ms / 128) * 4;
  int ga = (int)(Ms / 64) * 16;

  for (int s = 0; s < S; ++s) {
    const float* xs = x + (size_t)s * Ms * 512;
    k_split<<<gsplit, 256, 0, stream>>>(xs, xh, xl, n4x);
    k_gemm<0><<<gq, 256, 0, stream>>>(xh, xl, wqh, wql, 12, qb, vb, q, k, v,
                                      nullptr, nullptr);
    // attention writes its output (bf16 hi/lo) back into the x hi/lo buffers
    k_attn<<<ga, 256, 0, stream>>>(q, k, v, rpb, lsc, xh, xl);
    k_gemm<1><<<gp, 256, 0, stream>>>(xh, xl, wph, wpl, 4, nullptr, nullptr,
                                      nullptr, nullptr, nullptr, pb,
                                      out + (size_t)s * Ms * 512);
  }
  (void)in_sizes; (void)n_in; (void)out_size;
}